// Round 5
// baseline (450.292 us; speedup 1.0000x reference)
//
#include <hip/hip_runtime.h>

#define NN 50000
#define NE 800000
#define D  128
#define NC 40
#define NBLK ((NN + 255) / 256)   // 196 scan blocks

// ---------- edge loading (int32/int64 auto-detect) ----------
__device__ __forceinline__ void load_edge(const void* ei, int e, int is64, int& s, int& d) {
    if (is64) {
        const long long* p = (const long long*)ei;
        s = (int)p[e]; d = (int)p[NE + e];
    } else {
        const int* p = (const int*)ei;
        s = p[e]; d = p[NE + e];
    }
}

// flag=1 if edge_index is int64 (all sampled odd int32 words are zero)
__global__ void detect_kernel(const int* ei, int* flag) {
    __shared__ int nz;
    if (threadIdx.x == 0) nz = 0;
    __syncthreads();
    int c = 0;
    for (int i = threadIdx.x; i < 2048; i += 256)
        if (ei[2 * i + 1] != 0) c = 1;
    if (c) atomicAdd(&nz, 1);
    __syncthreads();
    if (threadIdx.x == 0) *flag = (nz == 0) ? 1 : 0;
}

__global__ void count_deg_kernel(const void* ei, const int* __restrict__ flag, int* deg) {
    int e = blockIdx.x * 256 + threadIdx.x;
    if (e >= NE) return;
    int is64 = *flag;
    int s, d; load_edge(ei, e, is64, s, d);
    if ((unsigned)d < NN) atomicAdd(&deg[d], 1);
}

// ---------- multi-block exclusive scan of deg -> rowptr (+ dinv fused) ----------
__global__ __launch_bounds__(256) void scan_part_kernel(const int* __restrict__ deg,
                                                        int* __restrict__ part) {
    __shared__ int s[256];
    int t = threadIdx.x, i = blockIdx.x * 256 + t;
    s[t] = (i < NN) ? deg[i] : 0;
    __syncthreads();
    for (int off = 128; off > 0; off >>= 1) {
        if (t < off) s[t] += s[t + off];
        __syncthreads();
    }
    if (t == 0) part[blockIdx.x] = s[0];
}

__global__ __launch_bounds__(256) void scan_mid_kernel(int* __restrict__ part,
                                                       int* __restrict__ rowptr) {
    __shared__ int s[256];
    int t = threadIdx.x;
    int v = (t < NBLK) ? part[t] : 0;
    s[t] = v;
    __syncthreads();
    for (int off = 1; off < 256; off <<= 1) {
        int u = (t >= off) ? s[t - off] : 0;
        __syncthreads();
        s[t] += u;
        __syncthreads();
    }
    if (t < NBLK) part[t] = s[t] - v;        // exclusive block offsets
    if (t == 255) rowptr[NN] = s[255];       // total edge count
}

__global__ __launch_bounds__(256) void scan_write_kernel(const int* __restrict__ deg,
                                                         const int* __restrict__ part,
                                                         int* __restrict__ rowptr,
                                                         float* __restrict__ dinv) {
    __shared__ int s[256];
    int t = threadIdx.x, i = blockIdx.x * 256 + t;
    int v = (i < NN) ? deg[i] : 0;
    s[t] = v;
    __syncthreads();
    for (int off = 1; off < 256; off <<= 1) {
        int u = (t >= off) ? s[t - off] : 0;
        __syncthreads();
        s[t] += u;
        __syncthreads();
    }
    if (i < NN) {
        rowptr[i] = part[blockIdx.x] + s[t] - v;
        dinv[i] = 1.0f / sqrtf((float)v + 1.0f);   // +1 = self-loop
    }
}

// scatter edge ids into CSR slots; weight precomputed
__global__ void fill_kernel(const void* ei, const int* __restrict__ flag,
                            const int* __restrict__ rowptr, int* cursor,
                            const float* __restrict__ dinv,
                            int* __restrict__ srcs, float* __restrict__ wts) {
    int e = blockIdx.x * 256 + threadIdx.x;
    if (e >= NE) return;
    int is64 = *flag;
    int s, d; load_edge(ei, e, is64, s, d);
    if ((unsigned)s >= NN || (unsigned)d >= NN) return;
    int slot = rowptr[d] + atomicAdd(&cursor[d], 1);
    srcs[slot] = s;
    wts[slot] = dinv[s] * dinv[d];
}

// ---------- GEMM: T[M x 128] = A[M x 128] @ W[128 x 128] ----------
// Block 256 thr (4 waves), tile 128 rows. Wave owns 32 rows x 128 cols;
// lane owns cols (2*lane, 2*lane+1). Per k: W = one b64/lane from LDS
// (2-way alias, free; full 512B unique per instr), reused over 32 rows;
// A = wave-uniform b128 broadcast (4 k-values per row, offset-immediate).
// Per 4k/wave: 256 FMA-instr vs 36 cheap LDS-instr -> VALU-bound.
__global__ __launch_bounds__(256) void gemm128_kernel(const float* __restrict__ A,
                                                      const float* __restrict__ W,
                                                      float* __restrict__ T) {
    __shared__ float sA[128 * 68];    // 34.8 KB: rows x 64-k chunk (pad 68)
    __shared__ float sW[64 * 128];    // 32 KB:   k-chunk x 128 cols
    int tid = threadIdx.x;
    int wave = tid >> 6, lane = tid & 63;
    int m0 = blockIdx.x * 128;
    float2 acc[32];
#pragma unroll
    for (int r = 0; r < 32; ++r) acc[r] = make_float2(0.f, 0.f);

    for (int k0 = 0; k0 < D; k0 += 64) {
        // stage W chunk: 64x128 = 2048 float4 -> 8 per thread
        const float4* Wg = (const float4*)(W + (size_t)k0 * D);
        float4* sW4 = (float4*)sW;
#pragma unroll
        for (int i = 0; i < 8; ++i) sW4[tid + i * 256] = Wg[tid + i * 256];
        // stage A chunk: 128 rows x 64 cols; 2 threads per row
        {
            int row = tid >> 1, half = tid & 1;
            int grow = m0 + row;
            const float* Ap = A + (size_t)grow * D + k0 + half * 32;
            float* dst = &sA[row * 68 + half * 32];
#pragma unroll
            for (int i = 0; i < 8; ++i) {
                float4 v = make_float4(0, 0, 0, 0);
                if (grow < NN) v = *(const float4*)(Ap + i * 4);
                *(float4*)(dst + i * 4) = v;
            }
        }
        __syncthreads();
        const float* sAw = &sA[(wave * 32) * 68];
        for (int kk = 0; kk < 64; kk += 4) {
            float2 w0 = *(const float2*)&sW[(kk + 0) * 128 + 2 * lane];
            float2 w1 = *(const float2*)&sW[(kk + 1) * 128 + 2 * lane];
            float2 w2 = *(const float2*)&sW[(kk + 2) * 128 + 2 * lane];
            float2 w3 = *(const float2*)&sW[(kk + 3) * 128 + 2 * lane];
#pragma unroll
            for (int r = 0; r < 32; ++r) {
                float4 a = *(const float4*)&sAw[r * 68 + kk];   // broadcast
                acc[r].x = fmaf(a.x, w0.x, acc[r].x);
                acc[r].y = fmaf(a.x, w0.y, acc[r].y);
                acc[r].x = fmaf(a.y, w1.x, acc[r].x);
                acc[r].y = fmaf(a.y, w1.y, acc[r].y);
                acc[r].x = fmaf(a.z, w2.x, acc[r].x);
                acc[r].y = fmaf(a.z, w2.y, acc[r].y);
                acc[r].x = fmaf(a.w, w3.x, acc[r].x);
                acc[r].y = fmaf(a.w, w3.y, acc[r].y);
            }
        }
        __syncthreads();
    }
#pragma unroll
    for (int r = 0; r < 32; ++r) {
        int grow = m0 + wave * 32 + r;
        if (grow < NN) *(float2*)(T + (size_t)grow * D + 2 * lane) = acc[r];
    }
}

// ---------- CSR pull: out[d] = relu( sum_in(T[s]*w) + T[d]*dinv^2 + b ) ----------
// one 64-lane wave per dst node; two 32-lane halves process edge pairs
// (float4 per lane = full 512B row per half); shfl_xor(32) combines halves.
__global__ __launch_bounds__(256) void aggregate_kernel(const float* __restrict__ T,
                                                        const int* __restrict__ rowptr,
                                                        const int* __restrict__ srcs,
                                                        const float* __restrict__ wts,
                                                        const float* __restrict__ dinv,
                                                        const float* __restrict__ b,
                                                        float* __restrict__ out) {
    int wid = (blockIdx.x * 256 + threadIdx.x) >> 6;
    int lane = threadIdx.x & 63;
    int h = lane >> 5, l = lane & 31;
    if (wid >= NN) return;
    float di = dinv[wid];
    float wself = h ? 0.0f : di * di;
    float4 acc = ((const float4*)(T + (size_t)wid * D))[l];
    acc.x *= wself; acc.y *= wself; acc.z *= wself; acc.w *= wself;
    int beg = rowptr[wid], end = rowptr[wid + 1];
    int e = beg;
    for (; e + 7 < end; e += 8) {
        int e0 = e + h, e1 = e + 2 + h, e2 = e + 4 + h, e3 = e + 6 + h;
        int s0 = srcs[e0], s1 = srcs[e1], s2 = srcs[e2], s3 = srcs[e3];
        float w0 = wts[e0], w1 = wts[e1], w2 = wts[e2], w3 = wts[e3];
        float4 v0 = ((const float4*)(T + (size_t)s0 * D))[l];
        float4 v1 = ((const float4*)(T + (size_t)s1 * D))[l];
        float4 v2 = ((const float4*)(T + (size_t)s2 * D))[l];
        float4 v3 = ((const float4*)(T + (size_t)s3 * D))[l];
        acc.x = fmaf(v0.x, w0, acc.x); acc.y = fmaf(v0.y, w0, acc.y);
        acc.z = fmaf(v0.z, w0, acc.z); acc.w = fmaf(v0.w, w0, acc.w);
        acc.x = fmaf(v1.x, w1, acc.x); acc.y = fmaf(v1.y, w1, acc.y);
        acc.z = fmaf(v1.z, w1, acc.z); acc.w = fmaf(v1.w, w1, acc.w);
        acc.x = fmaf(v2.x, w2, acc.x); acc.y = fmaf(v2.y, w2, acc.y);
        acc.z = fmaf(v2.z, w2, acc.z); acc.w = fmaf(v2.w, w2, acc.w);
        acc.x = fmaf(v3.x, w3, acc.x); acc.y = fmaf(v3.y, w3, acc.y);
        acc.z = fmaf(v3.z, w3, acc.z); acc.w = fmaf(v3.w, w3, acc.w);
    }
    for (; e + 1 < end; e += 2) {
        int ee = e + h;
        int s0 = srcs[ee];
        float w0 = wts[ee];
        float4 v0 = ((const float4*)(T + (size_t)s0 * D))[l];
        acc.x = fmaf(v0.x, w0, acc.x); acc.y = fmaf(v0.y, w0, acc.y);
        acc.z = fmaf(v0.z, w0, acc.z); acc.w = fmaf(v0.w, w0, acc.w);
    }
    if (e < end) {                       // one leftover edge; h==1 contributes 0
        int ee = (e + h < end) ? e + h : end - 1;
        float w0 = (e + h < end) ? wts[ee] : 0.0f;
        int s0 = srcs[ee];
        float4 v0 = ((const float4*)(T + (size_t)s0 * D))[l];
        acc.x = fmaf(v0.x, w0, acc.x); acc.y = fmaf(v0.y, w0, acc.y);
        acc.z = fmaf(v0.z, w0, acc.z); acc.w = fmaf(v0.w, w0, acc.w);
    }
    acc.x += __shfl_xor(acc.x, 32);
    acc.y += __shfl_xor(acc.y, 32);
    acc.z += __shfl_xor(acc.z, 32);
    acc.w += __shfl_xor(acc.w, 32);
    if (h == 0) {
        float4 bb = ((const float4*)b)[l];
        acc.x = fmaxf(acc.x + bb.x, 0.0f);
        acc.y = fmaxf(acc.y + bb.y, 0.0f);
        acc.z = fmaxf(acc.z + bb.z, 0.0f);
        acc.w = fmaxf(acc.w + bb.w, 0.0f);
        ((float4*)(out + (size_t)wid * D))[l] = acc;
    }
}

// O[M x 40] = A[M x 128] @ W[128 x 40] + b
__global__ __launch_bounds__(256) void fc_kernel(const float* __restrict__ A,
                                                 const float* __restrict__ W,
                                                 const float* __restrict__ b,
                                                 float* __restrict__ O) {
    __shared__ float sW[D * NC];
    __shared__ float sH[64 * D];
    int tid = threadIdx.x;
    for (int i = tid; i < D * NC; i += 256) sW[i] = W[i];
    int m0 = blockIdx.x * 64;
#pragma unroll
    for (int i = 0; i < 32; ++i) {
        int idx = tid + i * 256;
        int row = idx >> 7, col = idx & 127;
        int grow = m0 + row;
        float v = (grow < NN) ? A[(size_t)grow * D + col] : 0.0f;
        sH[row * D + (col ^ ((row & 7) << 2))] = v;
    }
    __syncthreads();
    int r = tid >> 2, c0 = (tid & 3) * 10;
    int sw = (r & 7) << 2;
    float acc[10];
#pragma unroll
    for (int j = 0; j < 10; ++j) acc[j] = 0.0f;
    for (int k = 0; k < D; ++k) {
        float a = sH[r * D + (k ^ sw)];
#pragma unroll
        for (int j = 0; j < 10; ++j) acc[j] = fmaf(a, sW[k * NC + c0 + j], acc[j]);
    }
    int grow = m0 + r;
    if (grow < NN) {
#pragma unroll
        for (int j = 0; j < 10; ++j) O[(size_t)grow * NC + c0 + j] = acc[j] + b[c0 + j];
    }
}

extern "C" void kernel_launch(void* const* d_in, const int* in_sizes, int n_in,
                              void* d_out, int out_size, void* d_ws, size_t ws_size,
                              hipStream_t stream) {
    const float* x   = (const float*)d_in[0];
    const void*  ei  = d_in[1];
    const float* W1  = (const float*)d_in[2];
    const float* b1  = (const float*)d_in[3];
    const float* W2  = (const float*)d_in[4];
    const float* b2  = (const float*)d_in[5];
    const float* W3  = (const float*)d_in[6];
    const float* b3  = (const float*)d_in[7];
    const float* fcW = (const float*)d_in[8];
    const float* fcb = (const float*)d_in[9];

    float* out_h  = (float*)d_out;                       // [NN x 128]
    float* out_fc = out_h + (size_t)NN * D;              // [NN x 40]

    size_t off = 0;
    auto alloc = [&](size_t bytes) {
        void* p = (char*)d_ws + off;
        off += (bytes + 255) & ~(size_t)255;
        return p;
    };
    float* dinv   = (float*)alloc((size_t)NN * 4);
    int*   deg    = (int*)  alloc((size_t)NN * 4);
    int*   flag   = (int*)  alloc(256);
    int*   part   = (int*)  alloc((size_t)NBLK * 4);
    int*   rowptr = (int*)  alloc((size_t)(NN + 1) * 4);
    int*   cursor = (int*)  alloc((size_t)NN * 4);
    int*   srcs   = (int*)  alloc((size_t)NE * 4);
    float* wts    = (float*)alloc((size_t)NE * 4);
    float* bufT   = (float*)alloc((size_t)NN * D * 4);
    float* bufH   = (float*)alloc((size_t)NN * D * 4);
    (void)ws_size; (void)in_sizes; (void)n_in; (void)out_size;

    hipMemsetAsync(deg, 0, (size_t)NN * 4, stream);
    hipMemsetAsync(cursor, 0, (size_t)NN * 4, stream);
    detect_kernel<<<1, 256, 0, stream>>>((const int*)ei, flag);
    count_deg_kernel<<<(NE + 255) / 256, 256, 0, stream>>>(ei, flag, deg);
    scan_part_kernel<<<NBLK, 256, 0, stream>>>(deg, part);
    scan_mid_kernel<<<1, 256, 0, stream>>>(part, rowptr);
    scan_write_kernel<<<NBLK, 256, 0, stream>>>(deg, part, rowptr, dinv);
    fill_kernel<<<(NE + 255) / 256, 256, 0, stream>>>(ei, flag, rowptr, cursor, dinv, srcs, wts);

    auto layer = [&](const float* in, const float* W, const float* b, float* out) {
        gemm128_kernel<<<(NN + 127) / 128, 256, 0, stream>>>(in, W, bufT);
        aggregate_kernel<<<(NN * 64 + 255) / 256, 256, 0, stream>>>(bufT, rowptr, srcs, wts, dinv, b, out);
    };

    layer(x,    W1, b1, bufH);
    layer(bufH, W2, b2, bufH);   // aggregate reads only bufT; overwrite of bufH is safe
    layer(bufH, W3, b3, out_h);

    fc_kernel<<<(NN + 63) / 64, 256, 0, stream>>>(out_h, fcW, fcb, out_fc);
}

// Round 6
// 402.777 us; speedup vs baseline: 1.1180x; 1.1180x over previous
//
#include <hip/hip_runtime.h>

#define NN 50000
#define NE 800000
#define D  128
#define NC 40
#define NBLK ((NN + 255) / 256)   // 196 scan blocks

// ---------- edge loading (int32/int64 auto-detect) ----------
__device__ __forceinline__ void load_edge(const void* ei, int e, int is64, int& s, int& d) {
    if (is64) {
        const long long* p = (const long long*)ei;
        s = (int)p[e]; d = (int)p[NE + e];
    } else {
        const int* p = (const int*)ei;
        s = p[e]; d = p[NE + e];
    }
}

// flag=1 if edge_index is int64 (all sampled odd int32 words are zero)
__global__ void detect_kernel(const int* ei, int* flag) {
    __shared__ int nz;
    if (threadIdx.x == 0) nz = 0;
    __syncthreads();
    int c = 0;
    for (int i = threadIdx.x; i < 2048; i += 256)
        if (ei[2 * i + 1] != 0) c = 1;
    if (c) atomicAdd(&nz, 1);
    __syncthreads();
    if (threadIdx.x == 0) *flag = (nz == 0) ? 1 : 0;
}

__global__ void count_deg_kernel(const void* ei, const int* __restrict__ flag, int* deg) {
    int e = blockIdx.x * 256 + threadIdx.x;
    if (e >= NE) return;
    int is64 = *flag;
    int s, d; load_edge(ei, e, is64, s, d);
    if ((unsigned)d < NN) atomicAdd(&deg[d], 1);
}

// ---------- multi-block exclusive scan of deg -> rowptr (+ dinv fused) ----------
__global__ __launch_bounds__(256) void scan_part_kernel(const int* __restrict__ deg,
                                                        int* __restrict__ part) {
    __shared__ int s[256];
    int t = threadIdx.x, i = blockIdx.x * 256 + t;
    s[t] = (i < NN) ? deg[i] : 0;
    __syncthreads();
    for (int off = 128; off > 0; off >>= 1) {
        if (t < off) s[t] += s[t + off];
        __syncthreads();
    }
    if (t == 0) part[blockIdx.x] = s[0];
}

__global__ __launch_bounds__(256) void scan_mid_kernel(int* __restrict__ part,
                                                       int* __restrict__ rowptr) {
    __shared__ int s[256];
    int t = threadIdx.x;
    int v = (t < NBLK) ? part[t] : 0;
    s[t] = v;
    __syncthreads();
    for (int off = 1; off < 256; off <<= 1) {
        int u = (t >= off) ? s[t - off] : 0;
        __syncthreads();
        s[t] += u;
        __syncthreads();
    }
    if (t < NBLK) part[t] = s[t] - v;        // exclusive block offsets
    if (t == 255) rowptr[NN] = s[255];       // total edge count
}

__global__ __launch_bounds__(256) void scan_write_kernel(const int* __restrict__ deg,
                                                         const int* __restrict__ part,
                                                         int* __restrict__ rowptr,
                                                         float* __restrict__ dinv) {
    __shared__ int s[256];
    int t = threadIdx.x, i = blockIdx.x * 256 + t;
    int v = (i < NN) ? deg[i] : 0;
    s[t] = v;
    __syncthreads();
    for (int off = 1; off < 256; off <<= 1) {
        int u = (t >= off) ? s[t - off] : 0;
        __syncthreads();
        s[t] += u;
        __syncthreads();
    }
    if (i < NN) {
        rowptr[i] = part[blockIdx.x] + s[t] - v;
        dinv[i] = 1.0f / sqrtf((float)v + 1.0f);   // +1 = self-loop
    }
}

// scatter edge ids into CSR slots; weight precomputed
__global__ void fill_kernel(const void* ei, const int* __restrict__ flag,
                            const int* __restrict__ rowptr, int* cursor,
                            const float* __restrict__ dinv,
                            int* __restrict__ srcs, float* __restrict__ wts) {
    int e = blockIdx.x * 256 + threadIdx.x;
    if (e >= NE) return;
    int is64 = *flag;
    int s, d; load_edge(ei, e, is64, s, d);
    if ((unsigned)s >= NN || (unsigned)d >= NN) return;
    int slot = rowptr[d] + atomicAdd(&cursor[d], 1);
    srcs[slot] = s;
    wts[slot] = dinv[s] * dinv[d];
}

// ---------- GEMM: T[M x 128] = A[M x 128] @ W[128 x 128] ----------
// Tile 128x128, 256 threads, 8x8 micro-tile (rows ty*8..+7, cols tx*4..+3 and
// 64+tx*4..+3). A staged TRANSPOSED [k][row] (pad 132) so the 8 rows are 2
// b128 reads (4-addr broadcast, conflict-free); W rows give 2 b128 reads at
// 2-way bank alias (free). Per k per wave: 4 DS instrs vs 64 FMA instrs ->
// VALU-bound (4 waves x ~20cyc DS = 80 < 128cyc VALU window per CU).
__global__ __launch_bounds__(256) void gemm128_kernel(const float* __restrict__ A,
                                                      const float* __restrict__ W,
                                                      float* __restrict__ T) {
    __shared__ float sAT[32][132];    // 16.9 KB  [k][row]
    __shared__ float sW[32][128];     // 16 KB    [k][col]
    int tid = threadIdx.x;
    int tx = tid & 15;                // col group
    int ty = tid >> 4;                // row group
    int m0 = blockIdx.x * 128;
    float acc[8][8];
#pragma unroll
    for (int i = 0; i < 8; ++i)
#pragma unroll
        for (int j = 0; j < 8; ++j) acc[i][j] = 0.0f;

    for (int k0 = 0; k0 < D; k0 += 32) {
        // stage W chunk: 32x128 = 1024 float4, 4 per thread
        const float4* Wg = (const float4*)(W + (size_t)k0 * D);
#pragma unroll
        for (int i = 0; i < 4; ++i) ((float4*)sW)[tid + i * 256] = Wg[tid + i * 256];
        // stage A chunk transposed: 128 rows x 32 k
#pragma unroll
        for (int i = 0; i < 4; ++i) {
            int idx = tid + i * 256;       // 0..1023
            int row = idx >> 3;            // 0..127
            int kq = idx & 7;              // float4 within chunk
            float4 v = make_float4(0, 0, 0, 0);
            int grow = m0 + row;
            if (grow < NN) v = *(const float4*)(A + (size_t)grow * D + k0 + kq * 4);
            sAT[kq * 4 + 0][row] = v.x;
            sAT[kq * 4 + 1][row] = v.y;
            sAT[kq * 4 + 2][row] = v.z;
            sAT[kq * 4 + 3][row] = v.w;
        }
        __syncthreads();
#pragma unroll 4
        for (int k = 0; k < 32; ++k) {
            float a[8], w[8];
            *(float4*)&a[0] = *(const float4*)&sAT[k][ty * 8];
            *(float4*)&a[4] = *(const float4*)&sAT[k][ty * 8 + 4];
            *(float4*)&w[0] = *(const float4*)&sW[k][tx * 4];
            *(float4*)&w[4] = *(const float4*)&sW[k][64 + tx * 4];
#pragma unroll
            for (int i = 0; i < 8; ++i)
#pragma unroll
                for (int j = 0; j < 8; ++j)
                    acc[i][j] = fmaf(a[i], w[j], acc[i][j]);
        }
        __syncthreads();
    }
#pragma unroll
    for (int i = 0; i < 8; ++i) {
        int grow = m0 + ty * 8 + i;
        if (grow < NN) {
            float* O = T + (size_t)grow * D;
            *(float4*)(O + tx * 4)      = *(float4*)&acc[i][0];
            *(float4*)(O + 64 + tx * 4) = *(float4*)&acc[i][4];
        }
    }
}

// ---------- CSR pull: out[d] = relu( sum_in(T[s]*w) + T[d]*dinv^2 + b ) ----------
// one 64-lane wave per dst node; two 32-lane halves process edge pairs
// (float4 per lane = full 512B row per half); shfl_xor(32) combines halves.
__global__ __launch_bounds__(256) void aggregate_kernel(const float* __restrict__ T,
                                                        const int* __restrict__ rowptr,
                                                        const int* __restrict__ srcs,
                                                        const float* __restrict__ wts,
                                                        const float* __restrict__ dinv,
                                                        const float* __restrict__ b,
                                                        float* __restrict__ out) {
    int wid = (blockIdx.x * 256 + threadIdx.x) >> 6;
    int lane = threadIdx.x & 63;
    int h = lane >> 5, l = lane & 31;
    if (wid >= NN) return;
    float di = dinv[wid];
    float wself = h ? 0.0f : di * di;
    float4 acc = ((const float4*)(T + (size_t)wid * D))[l];
    acc.x *= wself; acc.y *= wself; acc.z *= wself; acc.w *= wself;
    int beg = rowptr[wid], end = rowptr[wid + 1];
    int e = beg;
    for (; e + 7 < end; e += 8) {
        int e0 = e + h, e1 = e + 2 + h, e2 = e + 4 + h, e3 = e + 6 + h;
        int s0 = srcs[e0], s1 = srcs[e1], s2 = srcs[e2], s3 = srcs[e3];
        float w0 = wts[e0], w1 = wts[e1], w2 = wts[e2], w3 = wts[e3];
        float4 v0 = ((const float4*)(T + (size_t)s0 * D))[l];
        float4 v1 = ((const float4*)(T + (size_t)s1 * D))[l];
        float4 v2 = ((const float4*)(T + (size_t)s2 * D))[l];
        float4 v3 = ((const float4*)(T + (size_t)s3 * D))[l];
        acc.x = fmaf(v0.x, w0, acc.x); acc.y = fmaf(v0.y, w0, acc.y);
        acc.z = fmaf(v0.z, w0, acc.z); acc.w = fmaf(v0.w, w0, acc.w);
        acc.x = fmaf(v1.x, w1, acc.x); acc.y = fmaf(v1.y, w1, acc.y);
        acc.z = fmaf(v1.z, w1, acc.z); acc.w = fmaf(v1.w, w1, acc.w);
        acc.x = fmaf(v2.x, w2, acc.x); acc.y = fmaf(v2.y, w2, acc.y);
        acc.z = fmaf(v2.z, w2, acc.z); acc.w = fmaf(v2.w, w2, acc.w);
        acc.x = fmaf(v3.x, w3, acc.x); acc.y = fmaf(v3.y, w3, acc.y);
        acc.z = fmaf(v3.z, w3, acc.z); acc.w = fmaf(v3.w, w3, acc.w);
    }
    for (; e + 1 < end; e += 2) {
        int ee = e + h;
        int s0 = srcs[ee];
        float w0 = wts[ee];
        float4 v0 = ((const float4*)(T + (size_t)s0 * D))[l];
        acc.x = fmaf(v0.x, w0, acc.x); acc.y = fmaf(v0.y, w0, acc.y);
        acc.z = fmaf(v0.z, w0, acc.z); acc.w = fmaf(v0.w, w0, acc.w);
    }
    if (e < end) {                       // one leftover edge; h==1 contributes 0
        int ee = (e + h < end) ? e + h : end - 1;
        float w0 = (e + h < end) ? wts[ee] : 0.0f;
        int s0 = srcs[ee];
        float4 v0 = ((const float4*)(T + (size_t)s0 * D))[l];
        acc.x = fmaf(v0.x, w0, acc.x); acc.y = fmaf(v0.y, w0, acc.y);
        acc.z = fmaf(v0.z, w0, acc.z); acc.w = fmaf(v0.w, w0, acc.w);
    }
    acc.x += __shfl_xor(acc.x, 32);
    acc.y += __shfl_xor(acc.y, 32);
    acc.z += __shfl_xor(acc.z, 32);
    acc.w += __shfl_xor(acc.w, 32);
    if (h == 0) {
        float4 bb = ((const float4*)b)[l];
        acc.x = fmaxf(acc.x + bb.x, 0.0f);
        acc.y = fmaxf(acc.y + bb.y, 0.0f);
        acc.z = fmaxf(acc.z + bb.z, 0.0f);
        acc.w = fmaxf(acc.w + bb.w, 0.0f);
        ((float4*)(out + (size_t)wid * D))[l] = acc;
    }
}

// O[M x 40] = A[M x 128] @ W[128 x 40] + b
__global__ __launch_bounds__(256) void fc_kernel(const float* __restrict__ A,
                                                 const float* __restrict__ W,
                                                 const float* __restrict__ b,
                                                 float* __restrict__ O) {
    __shared__ float sW[D * NC];
    __shared__ float sH[64 * D];
    int tid = threadIdx.x;
    for (int i = tid; i < D * NC; i += 256) sW[i] = W[i];
    int m0 = blockIdx.x * 64;
#pragma unroll
    for (int i = 0; i < 32; ++i) {
        int idx = tid + i * 256;
        int row = idx >> 7, col = idx & 127;
        int grow = m0 + row;
        float v = (grow < NN) ? A[(size_t)grow * D + col] : 0.0f;
        sH[row * D + (col ^ ((row & 7) << 2))] = v;
    }
    __syncthreads();
    int r = tid >> 2, c0 = (tid & 3) * 10;
    int sw = (r & 7) << 2;
    float acc[10];
#pragma unroll
    for (int j = 0; j < 10; ++j) acc[j] = 0.0f;
    for (int k = 0; k < D; ++k) {
        float a = sH[r * D + (k ^ sw)];
#pragma unroll
        for (int j = 0; j < 10; ++j) acc[j] = fmaf(a, sW[k * NC + c0 + j], acc[j]);
    }
    int grow = m0 + r;
    if (grow < NN) {
#pragma unroll
        for (int j = 0; j < 10; ++j) O[(size_t)grow * NC + c0 + j] = acc[j] + b[c0 + j];
    }
}

extern "C" void kernel_launch(void* const* d_in, const int* in_sizes, int n_in,
                              void* d_out, int out_size, void* d_ws, size_t ws_size,
                              hipStream_t stream) {
    const float* x   = (const float*)d_in[0];
    const void*  ei  = d_in[1];
    const float* W1  = (const float*)d_in[2];
    const float* b1  = (const float*)d_in[3];
    const float* W2  = (const float*)d_in[4];
    const float* b2  = (const float*)d_in[5];
    const float* W3  = (const float*)d_in[6];
    const float* b3  = (const float*)d_in[7];
    const float* fcW = (const float*)d_in[8];
    const float* fcb = (const float*)d_in[9];

    float* out_h  = (float*)d_out;                       // [NN x 128]
    float* out_fc = out_h + (size_t)NN * D;              // [NN x 40]

    size_t off = 0;
    auto alloc = [&](size_t bytes) {
        void* p = (char*)d_ws + off;
        off += (bytes + 255) & ~(size_t)255;
        return p;
    };
    float* dinv   = (float*)alloc((size_t)NN * 4);
    int*   deg    = (int*)  alloc((size_t)NN * 4);
    int*   flag   = (int*)  alloc(256);
    int*   part   = (int*)  alloc((size_t)NBLK * 4);
    int*   rowptr = (int*)  alloc((size_t)(NN + 1) * 4);
    int*   cursor = (int*)  alloc((size_t)NN * 4);
    int*   srcs   = (int*)  alloc((size_t)NE * 4);
    float* wts    = (float*)alloc((size_t)NE * 4);
    float* bufT   = (float*)alloc((size_t)NN * D * 4);
    float* bufH   = (float*)alloc((size_t)NN * D * 4);
    (void)ws_size; (void)in_sizes; (void)n_in; (void)out_size;

    hipMemsetAsync(deg, 0, (size_t)NN * 4, stream);
    hipMemsetAsync(cursor, 0, (size_t)NN * 4, stream);
    detect_kernel<<<1, 256, 0, stream>>>((const int*)ei, flag);
    count_deg_kernel<<<(NE + 255) / 256, 256, 0, stream>>>(ei, flag, deg);
    scan_part_kernel<<<NBLK, 256, 0, stream>>>(deg, part);
    scan_mid_kernel<<<1, 256, 0, stream>>>(part, rowptr);
    scan_write_kernel<<<NBLK, 256, 0, stream>>>(deg, part, rowptr, dinv);
    fill_kernel<<<(NE + 255) / 256, 256, 0, stream>>>(ei, flag, rowptr, cursor, dinv, srcs, wts);

    auto layer = [&](const float* in, const float* W, const float* b, float* out) {
        gemm128_kernel<<<(NN + 127) / 128, 256, 0, stream>>>(in, W, bufT);
        aggregate_kernel<<<(NN * 64 + 255) / 256, 256, 0, stream>>>(bufT, rowptr, srcs, wts, dinv, b, out);
    };

    layer(x,    W1, b1, bufH);
    layer(bufH, W2, b2, bufH);   // aggregate reads only bufT; overwrite of bufH is safe
    layer(bufH, W3, b3, out_h);

    fc_kernel<<<(NN + 63) / 64, 256, 0, stream>>>(out_h, fcW, fcb, out_fc);
}